// Round 2
// baseline (768.475 us; speedup 1.0000x reference)
//
#include <hip/hip_runtime.h>
#include <math.h>

typedef __attribute__((ext_vector_type(8))) _Float16 half8;  // 8 fp16 = 4 VGPRs
typedef __attribute__((ext_vector_type(8))) short short8;
typedef __attribute__((ext_vector_type(4))) float float4v;

// ---------------- fp16 helpers ---------------------------------------------
static __device__ __forceinline__ unsigned short f2h(float f) {
  union { _Float16 h; unsigned short u; } c;
  c.h = (_Float16)f;
  return c.u;
}
static __device__ __forceinline__ float h2f(unsigned short u) {
  union { unsigned short u; _Float16 h; } c;
  c.u = u;
  return (float)c.h;
}

// Direct global->LDS async copy, 16B per lane. LDS dest must be wave-uniform
// base; lane l lands at dest + l*16.
static __device__ __forceinline__ void gload16(const unsigned short* g,
                                               unsigned short* l) {
  __builtin_amdgcn_global_load_lds(
      (const __attribute__((address_space(1))) unsigned int*)g,
      (__attribute__((address_space(3))) unsigned int*)l, 16, 0, 0);
}

// ---------------------------------------------------------------------------
// split_pack: weights [nmat][K][N] fp32 -> packed swizzled fp16 hi/lo k-tiles.
// Output layout: [mat][kt = k/32][N rows][32 halves], where within a tile the
// 16B chunk at logical (row, q) is stored at q' = q ^ ((row>>1)&3).  This is
// the exact LDS image expert_tower wants, so global_load_lds (linear) + a
// swizzled ds_read is conflict-free.
// ---------------------------------------------------------------------------
__global__ __launch_bounds__(256)
void split_pack(const float* __restrict__ src, unsigned short* __restrict__ dh,
                unsigned short* __restrict__ dl, int K, int N) {
  __shared__ float t[32][33];
  src += (size_t)blockIdx.z * K * N;
  const size_t tsz = (size_t)N * 32;  // ushorts per tile
  const size_t tb = ((size_t)blockIdx.z * (K >> 5) + blockIdx.x) * tsz;
  const int k0 = blockIdx.x * 32, n0 = blockIdx.y * 32;
  const int tid = threadIdx.x;
  const int r = tid >> 3, c4 = (tid & 7) * 4;

  const float4 v = *(const float4*)(src + (size_t)(k0 + r) * N + n0 + c4);
  t[r][c4 + 0] = v.x; t[r][c4 + 1] = v.y; t[r][c4 + 2] = v.z; t[r][c4 + 3] = v.w;
  __syncthreads();

  const int sel = tid >> 7;          // 0 = hi, 1 = lo
  const int rl = (tid >> 2) & 31;    // row within this 32-row slab
  const int qq = tid & 3;            // logical 16B chunk within row
  short8 vv;
  #pragma unroll
  for (int j = 0; j < 8; ++j) {
    const float f = t[qq * 8 + j][rl];
    const unsigned short hb = f2h(f);
    ((unsigned short*)&vv)[j] = sel ? f2h(f - h2f(hb)) : hb;
  }
  unsigned short* dst = (sel ? dl : dh) + tb +
      (size_t)(n0 + rl) * 32 + (qq ^ ((rl >> 1) & 3)) * 8;
  *(short8*)dst = vv;
}

// ---------------------------------------------------------------------------
// LN (+bias) + ReLU epilogue over N cols (4 waves, col-split), then store
// fp16 bits to dst[row * dstride + col]. Ends with a barrier.
// ---------------------------------------------------------------------------
template<int N, int NT>
__device__ __forceinline__ void ln_store_f16(
    float4v (*acc)[4], int w, int m, int q,
    const float* __restrict__ bias, const float* __restrict__ gamma,
    const float* __restrict__ beta,
    unsigned short* __restrict__ dst, int dstride,
    float (*sumP)[4], float (*sqP)[4]) {
  constexpr int NW = N / 4;
  float cb[NT], cg[NT], cbt[NT];
  #pragma unroll
  for (int t = 0; t < NT; ++t) {
    const int col = w * NW + t * 16 + m;
    cb[t] = bias[col]; cg[t] = gamma[col]; cbt[t] = beta[col];
  }
  #pragma unroll
  for (int s = 0; s < 4; ++s)
    #pragma unroll
    for (int r = 0; r < 4; ++r) {
      float s1 = 0.f, s2 = 0.f;
      #pragma unroll
      for (int t = 0; t < NT; ++t) {
        const float v = acc[s][t][r] + cb[t];
        s1 += v; s2 += v * v;
      }
      #pragma unroll
      for (int off = 1; off < 16; off <<= 1) {
        s1 += __shfl_xor(s1, off, 16);
        s2 += __shfl_xor(s2, off, 16);
      }
      if (m == 0) {
        sumP[s * 16 + q * 4 + r][w] = s1;
        sqP[s * 16 + q * 4 + r][w] = s2;
      }
    }
  __syncthreads();
  #pragma unroll
  for (int s = 0; s < 4; ++s)
    #pragma unroll
    for (int r = 0; r < 4; ++r) {
      const int row = s * 16 + q * 4 + r;
      const float S1 = sumP[row][0] + sumP[row][1] + sumP[row][2] + sumP[row][3];
      const float S2 = sqP[row][0] + sqP[row][1] + sqP[row][2] + sqP[row][3];
      const float mean = S1 * (1.f / N);
      const float var = S2 * (1.f / N) - mean * mean;
      const float inv = rsqrtf(var + 1e-5f);
      #pragma unroll
      for (int t = 0; t < NT; ++t) {
        const float o =
            fmaxf((acc[s][t][r] + cb[t] - mean) * inv * cg[t] + cbt[t], 0.f);
        dst[row * dstride + w * NW + t * 16 + m] = f2h(o);
      }
    }
  __syncthreads();
}

// ---------------------------------------------------------------------------
// Fused expert tower, pipelined.
// Phase 1: LDS double-buffered (A dbuf 16KB + B dbuf 64KB = 80KB exactly);
//   per k-step: stage kt+1 -> compute kt -> vmcnt(0) AFTER MFMA -> raw barrier.
// Phases 2/3: reg-staged prefetch (T14): global->reg loads for kt+1 issued
//   under MFMA of kt; two cheap raw barriers (lgkm drain only, no vmcnt).
// Pool layout (ushort offsets), all overlays barrier-protected:
//   P1 loop : lA buf b = b*4096 (hi +0, lo +2048); lB buf b = 8192+b*16384
//             (hi +0, lo +8192).  Total 40960 = 81920 B.
//   sumP/sqP: 16384..17408 (dead sub-buffer region during all epilogues)
//   hbuf    : 24064..40960 (written in P1 epilogue after internal sync)
//   P2 B buf: 0..16384 (hi/lo)      P3 B buf: 0..8192 (hi/lo)
//   rp      : 0..8704 (P3 epilogue, after internal sync)
// ---------------------------------------------------------------------------
__global__ __launch_bounds__(256, 2)
void expert_tower(const float* __restrict__ x,
                  const unsigned short* __restrict__ w1h,
                  const unsigned short* __restrict__ w1l,
                  const float* __restrict__ eb1, const float* __restrict__ eg1,
                  const float* __restrict__ ebt1,
                  const unsigned short* __restrict__ w2h,
                  const unsigned short* __restrict__ w2l,
                  const float* __restrict__ eb2, const float* __restrict__ eg2,
                  const float* __restrict__ ebt2,
                  const unsigned short* __restrict__ w3h,
                  const unsigned short* __restrict__ w3l,
                  const float* __restrict__ eb3, const float* __restrict__ eg3,
                  const float* __restrict__ ebt3,
                  unsigned short* __restrict__ eo, int B) {
  __shared__ __align__(16) unsigned short pool[40960];
  float (*sumP)[4] = (float (*)[4])(pool + 16384);
  float (*sqP)[4]  = (float (*)[4])(pool + 16896);
  unsigned short* hbuf = pool + 24064;

  const int tid = threadIdx.x;
  const int w = tid >> 6, lane = tid & 63, m = lane & 15, q = lane >> 4;
  const int qs8 = (q ^ ((m >> 1) & 3)) * 8;  // swizzled 16B slot (x8 ushorts)
  const int wb = w * 512;                    // per-wave 1KB chunk, in ushorts
  const int m0 = blockIdx.x * 64;
  const int e = blockIdx.y;
  const int arow = tid >> 2, ap = tid & 3;
  const int aswz = arow * 32 + (ap ^ ((arow >> 1) & 3)) * 8;

  eb1 += (size_t)e * 256; eg1 += (size_t)e * 256; ebt1 += (size_t)e * 256;
  eb2 += (size_t)e * 256; eg2 += (size_t)e * 256; ebt2 += (size_t)e * 256;
  eb3 += (size_t)e * 128; eg3 += (size_t)e * 128; ebt3 += (size_t)e * 128;

  float4v acc[4][4];

  // ================= phase 1: K=512, N=256, 3-term, LDS dbuf ================
  #pragma unroll
  for (int s = 0; s < 4; ++s)
    #pragma unroll
    for (int t = 0; t < 4; ++t) acc[s][t] = (float4v){0.f, 0.f, 0.f, 0.f};

  const float* xrow = x + (size_t)(m0 + arow) * 512 + ap * 8;
  float4 f0 = *(const float4*)xrow;
  float4 f1 = *(const float4*)(xrow + 4);

  {  // prologue: stage tile 0 into buf0
    const float fv[8] = {f0.x, f0.y, f0.z, f0.w, f1.x, f1.y, f1.z, f1.w};
    half8 ra, rla;
    #pragma unroll
    for (int j = 0; j < 8; ++j) {
      const _Float16 hb = (_Float16)fv[j];
      ra[j] = hb;
      rla[j] = (_Float16)(fv[j] - (float)hb);
    }
    *(half8*)(pool + aswz) = ra;
    *(half8*)(pool + 2048 + aswz) = rla;
    const size_t tb = ((size_t)(e * 16)) * 8192 + tid * 8;
    #pragma unroll
    for (int i = 0; i < 4; ++i) {
      gload16(w1h + tb + i * 2048, pool + 8192 + wb + i * 2048);
      gload16(w1l + tb + i * 2048, pool + 8192 + 8192 + wb + i * 2048);
    }
    f0 = *(const float4*)(xrow + 32);
    f1 = *(const float4*)(xrow + 36);
    __builtin_amdgcn_sched_barrier(0);
    asm volatile("s_waitcnt vmcnt(0) lgkmcnt(0)" ::: "memory");
    __builtin_amdgcn_sched_barrier(0);
    __builtin_amdgcn_s_barrier();
  }

  #pragma unroll 2
  for (int kt = 0; kt < 16; ++kt) {
    const int cur = kt & 1, nxt = cur ^ 1;
    if (kt < 15) {  // stage tile kt+1 into buf[nxt]
      const float fv[8] = {f0.x, f0.y, f0.z, f0.w, f1.x, f1.y, f1.z, f1.w};
      half8 ra, rla;
      #pragma unroll
      for (int j = 0; j < 8; ++j) {
        const _Float16 hb = (_Float16)fv[j];
        ra[j] = hb;
        rla[j] = (_Float16)(fv[j] - (float)hb);
      }
      *(half8*)(pool + nxt * 4096 + aswz) = ra;
      *(half8*)(pool + nxt * 4096 + 2048 + aswz) = rla;
      const size_t tb = ((size_t)(e * 16 + kt + 1)) * 8192 + tid * 8;
      #pragma unroll
      for (int i = 0; i < 4; ++i) {
        gload16(w1h + tb + i * 2048, pool + 8192 + nxt * 16384 + wb + i * 2048);
        gload16(w1l + tb + i * 2048,
                pool + 8192 + nxt * 16384 + 8192 + wb + i * 2048);
      }
      const int ktn = (kt < 14) ? kt + 2 : 15;
      f0 = *(const float4*)(xrow + ktn * 32);
      f1 = *(const float4*)(xrow + ktn * 32 + 4);
      __builtin_amdgcn_sched_barrier(0);  // pin staging before compute
    }
    half8 ah[4], al[4];
    const unsigned short* ab = pool + cur * 4096;
    #pragma unroll
    for (int s = 0; s < 4; ++s) {
      const int off = (s * 16 + m) * 32 + qs8;
      ah[s] = *(const half8*)(ab + off);
      al[s] = *(const half8*)(ab + 2048 + off);
    }
    const unsigned short* bb = pool + 8192 + cur * 16384;
    #pragma unroll
    for (int t = 0; t < 4; ++t) {
      const int boff = (w * 64 + t * 16 + m) * 32 + qs8;
      const half8 bh = *(const half8*)(bb + boff);
      const half8 bl = *(const half8*)(bb + 8192 + boff);
      #pragma unroll
      for (int s = 0; s < 4; ++s) {
        acc[s][t] = __builtin_amdgcn_mfma_f32_16x16x32_f16(ah[s], bh, acc[s][t], 0, 0, 0);
        acc[s][t] = __builtin_amdgcn_mfma_f32_16x16x32_f16(al[s], bh, acc[s][t], 0, 0, 0);
        acc[s][t] = __builtin_amdgcn_mfma_f32_16x16x32_f16(ah[s], bl, acc[s][t], 0, 0, 0);
      }
    }
    if (kt < 15) {
      __builtin_amdgcn_sched_barrier(0);  // keep MFMAs above the drain
      asm volatile("s_waitcnt vmcnt(0)" ::: "memory");
      __builtin_amdgcn_sched_barrier(0);
      __builtin_amdgcn_s_barrier();
    }
  }
  ln_store_f16<256, 4>(acc, w, m, q, eb1, eg1, ebt1, hbuf, 264, sumP, sqP);

  // ================= phase 2: K=256, N=256, 2-term, reg-staged ==============
  #pragma unroll
  for (int s = 0; s < 4; ++s)
    #pragma unroll
    for (int t = 0; t < 4; ++t) acc[s][t] = (float4v){0.f, 0.f, 0.f, 0.f};

  short8 rh[4], rl[4];
  {
    const size_t tb = ((size_t)(e * 8)) * 8192 + tid * 8;
    #pragma unroll
    for (int i = 0; i < 4; ++i) {
      rh[i] = *(const short8*)(w2h + tb + i * 2048);
      rl[i] = *(const short8*)(w2l + tb + i * 2048);
    }
  }
  for (int kt = 0; kt < 8; ++kt) {
    if (kt) __builtin_amdgcn_s_barrier();  // readers of tile kt-1 done
    #pragma unroll
    for (int i = 0; i < 4; ++i) {
      *(short8*)(pool + i * 2048 + tid * 8) = rh[i];
      *(short8*)(pool + 8192 + i * 2048 + tid * 8) = rl[i];
    }
    if (kt < 7) {  // prefetch tile kt+1 into regs (lands under MFMA below)
      const size_t tb = ((size_t)(e * 8 + kt + 1)) * 8192 + tid * 8;
      #pragma unroll
      for (int i = 0; i < 4; ++i) {
        rh[i] = *(const short8*)(w2h + tb + i * 2048);
        rl[i] = *(const short8*)(w2l + tb + i * 2048);
      }
    }
    __builtin_amdgcn_sched_barrier(0);
    asm volatile("s_waitcnt lgkmcnt(0)" ::: "memory");  // ds_writes visible
    __builtin_amdgcn_sched_barrier(0);
    __builtin_amdgcn_s_barrier();
    half8 ah[4];
    #pragma unroll
    for (int s = 0; s < 4; ++s)
      ah[s] = *(const half8*)(hbuf + (s * 16 + m) * 264 + kt * 32 + q * 8);
    #pragma unroll
    for (int t = 0; t < 4; ++t) {
      const int boff = (w * 64 + t * 16 + m) * 32 + qs8;
      const half8 bh = *(const half8*)(pool + boff);
      const half8 bl = *(const half8*)(pool + 8192 + boff);
      #pragma unroll
      for (int s = 0; s < 4; ++s) {
        acc[s][t] = __builtin_amdgcn_mfma_f32_16x16x32_f16(ah[s], bh, acc[s][t], 0, 0, 0);
        acc[s][t] = __builtin_amdgcn_mfma_f32_16x16x32_f16(ah[s], bl, acc[s][t], 0, 0, 0);
      }
    }
  }
  ln_store_f16<256, 4>(acc, w, m, q, eb2, eg2, ebt2, hbuf, 264, sumP, sqP);

  // ================= phase 3: K=256, N=128, 2-term, reg-staged ==============
  #pragma unroll
  for (int s = 0; s < 4; ++s)
    #pragma unroll
    for (int t = 0; t < 2; ++t) acc[s][t] = (float4v){0.f, 0.f, 0.f, 0.f};

  short8 sh[2], sl[2];
  {
    const size_t tb = ((size_t)(e * 8)) * 4096 + tid * 8;
    #pragma unroll
    for (int i = 0; i < 2; ++i) {
      sh[i] = *(const short8*)(w3h + tb + i * 2048);
      sl[i] = *(const short8*)(w3l + tb + i * 2048);
    }
  }
  for (int kt = 0; kt < 8; ++kt) {
    if (kt) __builtin_amdgcn_s_barrier();
    #pragma unroll
    for (int i = 0; i < 2; ++i) {
      *(short8*)(pool + i * 2048 + tid * 8) = sh[i];
      *(short8*)(pool + 4096 + i * 2048 + tid * 8) = sl[i];
    }
    if (kt < 7) {
      const size_t tb = ((size_t)(e * 8 + kt + 1)) * 4096 + tid * 8;
      #pragma unroll
      for (int i = 0; i < 2; ++i) {
        sh[i] = *(const short8*)(w3h + tb + i * 2048);
        sl[i] = *(const short8*)(w3l + tb + i * 2048);
      }
    }
    __builtin_amdgcn_sched_barrier(0);
    asm volatile("s_waitcnt lgkmcnt(0)" ::: "memory");
    __builtin_amdgcn_sched_barrier(0);
    __builtin_amdgcn_s_barrier();
    half8 ah[4];
    #pragma unroll
    for (int s = 0; s < 4; ++s)
      ah[s] = *(const half8*)(hbuf + (s * 16 + m) * 264 + kt * 32 + q * 8);
    #pragma unroll
    for (int t = 0; t < 2; ++t) {
      const int boff = (w * 32 + t * 16 + m) * 32 + qs8;
      const half8 bh = *(const half8*)(pool + boff);
      const half8 bl = *(const half8*)(pool + 4096 + boff);
      #pragma unroll
      for (int s = 0; s < 4; ++s) {
        acc[s][t] = __builtin_amdgcn_mfma_f32_16x16x32_f16(ah[s], bh, acc[s][t], 0, 0, 0);
        acc[s][t] = __builtin_amdgcn_mfma_f32_16x16x32_f16(ah[s], bl, acc[s][t], 0, 0, 0);
      }
    }
  }
  // epilogue 3 -> repack buffer (stride 136) -> coalesced fp16 stores to eo
  unsigned short* rp = pool;  // 64*136, overlays B buf (writes after sync)
  ln_store_f16<128, 2>(acc, w, m, q, eb3, eg3, ebt3, rp, 136, sumP, sqP);
  #pragma unroll
  for (int i = 0; i < 4; ++i) {
    const int c = tid + i * 256;
    const int rowc = c >> 4, c8 = c & 15;
    *(short8*)(eo + ((size_t)e * B + m0 + rowc) * 128 + c8 * 8) =
        *(const short8*)(rp + rowc * 136 + c8 * 8);
  }
}

// ---------------------------------------------------------------------------
// Gating hidden GEMM, same pipelined phase-1 skeleton (dbuf A+B, 32KB LDS).
// ---------------------------------------------------------------------------
__global__ __launch_bounds__(256, 4)
void gate_gemm(const float* __restrict__ x, const unsigned short* __restrict__ twh,
               const unsigned short* __restrict__ twl,
               const float* __restrict__ tg_b1, const float* __restrict__ sg_b1,
               float* __restrict__ gh, int B) {
  __shared__ __align__(16) unsigned short gp[16384];
  // A buf b: b*4096 (hi +0, lo +2048); B buf b: 8192 + b*4096 (hi +0, lo +2048)
  const int tid = threadIdx.x;
  const int w = tid >> 6, lane = tid & 63, m = lane & 15, q = lane >> 4;
  const int qs8 = (q ^ ((m >> 1) & 3)) * 8;
  const int wb = w * 512;
  const int m0 = blockIdx.x * 64;
  const int slice = blockIdx.y;
  const int arow = tid >> 2, ap = tid & 3;
  const int aswz = arow * 32 + (ap ^ ((arow >> 1) & 3)) * 8;
  const float* bias = (slice < 3) ? tg_b1 + (size_t)slice * 64 : sg_b1;

  float4v acc[4];
  #pragma unroll
  for (int s = 0; s < 4; ++s) acc[s] = (float4v){0.f, 0.f, 0.f, 0.f};

  const float* xrow = x + (size_t)(m0 + arow) * 512 + ap * 8;
  float4 f0 = *(const float4*)xrow;
  float4 f1 = *(const float4*)(xrow + 4);

  {  // prologue
    const float fv[8] = {f0.x, f0.y, f0.z, f0.w, f1.x, f1.y, f1.z, f1.w};
    half8 ra, rla;
    #pragma unroll
    for (int j = 0; j < 8; ++j) {
      const _Float16 hb = (_Float16)fv[j];
      ra[j] = hb;
      rla[j] = (_Float16)(fv[j] - (float)hb);
    }
    *(half8*)(gp + aswz) = ra;
    *(half8*)(gp + 2048 + aswz) = rla;
    const size_t tb = ((size_t)(slice * 16)) * 2048 + tid * 8;
    gload16(twh + tb, gp + 8192 + wb);
    gload16(twl + tb, gp + 8192 + 2048 + wb);
    f0 = *(const float4*)(xrow + 32);
    f1 = *(const float4*)(xrow + 36);
    __builtin_amdgcn_sched_barrier(0);
    asm volatile("s_waitcnt vmcnt(0) lgkmcnt(0)" ::: "memory");
    __builtin_amdgcn_sched_barrier(0);
    __builtin_amdgcn_s_barrier();
  }

  #pragma unroll 2
  for (int kt = 0; kt < 16; ++kt) {
    const int cur = kt & 1, nxt = cur ^ 1;
    if (kt < 15) {
      const float fv[8] = {f0.x, f0.y, f0.z, f0.w, f1.x, f1.y, f1.z, f1.w};
      half8 ra, rla;
      #pragma unroll
      for (int j = 0; j < 8; ++j) {
        const _Float16 hb = (_Float16)fv[j];
        ra[j] = hb;
        rla[j] = (_Float16)(fv[j] - (float)hb);
      }
      *(half8*)(gp + nxt * 4096 + aswz) = ra;
      *(half8*)(gp + nxt * 4096 + 2048 + aswz) = rla;
      const size_t tb = ((size_t)(slice * 16 + kt + 1)) * 2048 + tid * 8;
      gload16(twh + tb, gp + 8192 + nxt * 4096 + wb);
      gload16(twl + tb, gp + 8192 + nxt * 4096 + 2048 + wb);
      const int ktn = (kt < 14) ? kt + 2 : 15;
      f0 = *(const float4*)(xrow + ktn * 32);
      f1 = *(const float4*)(xrow + ktn * 32 + 4);
      __builtin_amdgcn_sched_barrier(0);
    }
    const unsigned short* ab = gp + cur * 4096;
    const unsigned short* bb = gp + 8192 + cur * 4096;
    const int boff = (w * 16 + m) * 32 + qs8;
    const half8 bh = *(const half8*)(bb + boff);
    const half8 bl = *(const half8*)(bb + 2048 + boff);
    #pragma unroll
    for (int s = 0; s < 4; ++s) {
      const int aoff = (s * 16 + m) * 32 + qs8;
      const half8 ah = *(const half8*)(ab + aoff);
      const half8 al = *(const half8*)(ab + 2048 + aoff);
      acc[s] = __builtin_amdgcn_mfma_f32_16x16x32_f16(ah, bh, acc[s], 0, 0, 0);
      acc[s] = __builtin_amdgcn_mfma_f32_16x16x32_f16(al, bh, acc[s], 0, 0, 0);
      acc[s] = __builtin_amdgcn_mfma_f32_16x16x32_f16(ah, bl, acc[s], 0, 0, 0);
    }
    if (kt < 15) {
      __builtin_amdgcn_sched_barrier(0);
      asm volatile("s_waitcnt vmcnt(0)" ::: "memory");
      __builtin_amdgcn_sched_barrier(0);
      __builtin_amdgcn_s_barrier();
    }
  }
  const float cb = bias[w * 16 + m];
  #pragma unroll
  for (int s = 0; s < 4; ++s)
    #pragma unroll
    for (int r = 0; r < 4; ++r) {
      const int row = m0 + s * 16 + q * 4 + r;
      gh[((size_t)slice * B + row) * 64 + w * 16 + m] =
          fmaxf(acc[s][r] + cb, 0.f);
    }
}

// ---------------------------------------------------------------------------
// Gating layer 2: softmax(gh @ w2 + b2) over NOUT outputs.
// ---------------------------------------------------------------------------
template<int NOUT>
__global__ __launch_bounds__(256)
void gate2(const float* __restrict__ gh, const float* __restrict__ w2,
           const float* __restrict__ b2, float* __restrict__ outw, int B) {
  const int b0 = blockIdx.x * 64;
  __shared__ float ghs[64][65];
  __shared__ float wls[64 * NOUT];
  __shared__ float bls[NOUT];
  const int tid = threadIdx.x;

  const float* src = gh + (size_t)b0 * 64;
  for (int f = tid; f < 64 * 16; f += 256) {
    const int r = f >> 4, c4 = f & 15;
    const float4 v = *(const float4*)(src + r * 64 + c4 * 4);
    ghs[r][c4 * 4 + 0] = v.x;
    ghs[r][c4 * 4 + 1] = v.y;
    ghs[r][c4 * 4 + 2] = v.z;
    ghs[r][c4 * 4 + 3] = v.w;
  }
  for (int f = tid; f < 64 * NOUT; f += 256) wls[f] = w2[f];
  if (tid < NOUT) bls[tid] = b2[tid];
  __syncthreads();

  if (tid < 64) {
    const int b = b0 + tid;
    float a[NOUT];
    #pragma unroll
    for (int n = 0; n < NOUT; ++n) a[n] = bls[n];
    for (int k = 0; k < 64; ++k) {
      const float g = ghs[tid][k];
      #pragma unroll
      for (int n = 0; n < NOUT; ++n) a[n] = fmaf(g, wls[k * NOUT + n], a[n]);
    }
    float mx = a[0];
    #pragma unroll
    for (int n = 1; n < NOUT; ++n) mx = fmaxf(mx, a[n]);
    float sum = 0.f;
    #pragma unroll
    for (int n = 0; n < NOUT; ++n) { a[n] = expf(a[n] - mx); sum += a[n]; }
    const float r = 1.f / sum;
    #pragma unroll
    for (int n = 0; n < NOUT; ++n) outw[(size_t)b * NOUT + n] = a[n] * r;
  }
}

// ---------------------------------------------------------------------------
// Final combine: out[s][b][:] = sum_e coef(s,e,b) * eo[e][b][:]  (eo fp16)
// ---------------------------------------------------------------------------
__global__ __launch_bounds__(256)
void combine(const unsigned short* __restrict__ eo, const float* __restrict__ gw,
             const float* __restrict__ sgw, float* __restrict__ out, int B) {
  const int tid = threadIdx.x;
  const int gb = blockIdx.x * 16 + (tid >> 4);
  const int c0 = (tid & 15) * 8;

  float a[4][8];
  #pragma unroll
  for (int s = 0; s < 4; ++s)
    #pragma unroll
    for (int i = 0; i < 8; ++i) a[s][i] = 0.f;

  #pragma unroll
  for (int e = 0; e < 10; ++e) {
    const half8 vv = *(const half8*)(eo + ((size_t)e * B + gb) * 128 + c0);
    float f[8];
    #pragma unroll
    for (int i = 0; i < 8; ++i) f[i] = (float)vv[i];
    float c[4];
    c[3] = sgw[(size_t)gb * 10 + e];
    c[0] = c[1] = c[2] = 0.f;
    if (e < 4) {
      c[0] = gw[((size_t)0 * B + gb) * 6 + e];
      c[1] = gw[((size_t)1 * B + gb) * 6 + e];
      c[2] = gw[((size_t)2 * B + gb) * 6 + e];
    } else {
      const int tt = (e - 4) >> 1;
      c[tt] = gw[((size_t)tt * B + gb) * 6 + 4 + ((e - 4) & 1)];
    }
    #pragma unroll
    for (int s = 0; s < 4; ++s)
      #pragma unroll
      for (int i = 0; i < 8; ++i) a[s][i] = fmaf(c[s], f[i], a[s][i]);
  }

  #pragma unroll
  for (int s = 0; s < 4; ++s) {
    float* p = out + ((size_t)s * B + gb) * 128 + c0;
    const float4 v0 = {a[s][0], a[s][1], a[s][2], a[s][3]};
    const float4 v1 = {a[s][4], a[s][5], a[s][6], a[s][7]};
    *(float4*)p = v0;
    *(float4*)(p + 4) = v1;
  }
}

// ---------------------------------------------------------------------------
extern "C" void kernel_launch(void* const* d_in, const int* in_sizes, int n_in,
                              void* d_out, int out_size, void* d_ws, size_t ws_size,
                              hipStream_t stream) {
  const float* x     = (const float*)d_in[0];
  const float* ew1   = (const float*)d_in[1];
  const float* eb1   = (const float*)d_in[2];
  const float* eg1   = (const float*)d_in[3];
  const float* ebt1  = (const float*)d_in[4];
  const float* ew2   = (const float*)d_in[5];
  const float* eb2   = (const float*)d_in[6];
  const float* eg2   = (const float*)d_in[7];
  const float* ebt2  = (const float*)d_in[8];
  const float* ew3   = (const float*)d_in[9];
  const float* eb3   = (const float*)d_in[10];
  const float* eg3   = (const float*)d_in[11];
  const float* ebt3  = (const float*)d_in[12];
  const float* tg_w1 = (const float*)d_in[13];
  const float* tg_b1 = (const float*)d_in[14];
  const float* tg_w2 = (const float*)d_in[15];
  const float* tg_b2 = (const float*)d_in[16];
  const float* sg_w1 = (const float*)d_in[17];
  const float* sg_b1 = (const float*)d_in[18];
  const float* sg_w2 = (const float*)d_in[19];
  const float* sg_b2 = (const float*)d_in[20];
  float* out = (float*)d_out;

  const int B = 32768, D = 512, H = 256, O = 128, G = 64, E = 10;
  (void)D; (void)H; (void)O; (void)G;

  // ---- workspace (bytes), total ~97 MB ----
  char* p = (char*)d_ws;
  unsigned short* w1h  = (unsigned short*)p; p += (size_t)E * 16 * 8192 * 2;
  unsigned short* w1l  = (unsigned short*)p; p += (size_t)E * 16 * 8192 * 2;
  unsigned short* w2h  = (unsigned short*)p; p += (size_t)E * 8 * 8192 * 2;
  unsigned short* w2l  = (unsigned short*)p; p += (size_t)E * 8 * 8192 * 2;
  unsigned short* w3h  = (unsigned short*)p; p += (size_t)E * 8 * 4096 * 2;
  unsigned short* w3l  = (unsigned short*)p; p += (size_t)E * 8 * 4096 * 2;
  unsigned short* twh  = (unsigned short*)p; p += (size_t)4 * 16 * 2048 * 2;
  unsigned short* twl  = (unsigned short*)p; p += (size_t)4 * 16 * 2048 * 2;
  float* gwb  = (float*)p; p += (size_t)3 * B * 6 * 4;
  float* sgwb = (float*)p; p += (size_t)B * 10 * 4;
  unsigned short* eo = (unsigned short*)p;   // E*B*O fp16 = 83.9 MB
  float* gh = (float*)eo;                    // overlay: gating phase only

  // ---- 1. weight conversions (fp16 split, packed swizzled k-tiles) ----
  split_pack<<<dim3(16, 8, E), 256, 0, stream>>>(ew1, w1h, w1l, 512, 256);
  split_pack<<<dim3(8, 8, E), 256, 0, stream>>>(ew2, w2h, w2l, 256, 256);
  split_pack<<<dim3(8, 4, E), 256, 0, stream>>>(ew3, w3h, w3l, 256, 128);
  split_pack<<<dim3(16, 2, 3), 256, 0, stream>>>(tg_w1, twh, twl, 512, 64);
  split_pack<<<dim3(16, 2, 1), 256, 0, stream>>>(
      sg_w1, twh + (size_t)3 * 16 * 2048, twl + (size_t)3 * 16 * 2048, 512, 64);

  // ---- 2. gating ----
  gate_gemm<<<dim3(B / 64, 4), 256, 0, stream>>>(x, twh, twl, tg_b1, sg_b1,
                                                 gh, B);
  for (int t = 0; t < 3; ++t)
    gate2<6><<<B / 64, 256, 0, stream>>>(gh + (size_t)t * B * G,
                                         tg_w2 + (size_t)t * G * 6,
                                         tg_b2 + (size_t)t * 6,
                                         gwb + (size_t)t * B * 6, B);
  gate2<10><<<B / 64, 256, 0, stream>>>(gh + (size_t)3 * B * G, sg_w2, sg_b2,
                                        sgwb, B);

  // ---- 3. fused expert towers: one launch, all experts ----
  expert_tower<<<dim3(B / 64, E), 256, 0, stream>>>(
      x, w1h, w1l, eb1, eg1, ebt1, w2h, w2l, eb2, eg2, ebt2,
      w3h, w3l, eb3, eg3, ebt3, eo, B);

  // ---- 4. combine ----
  combine<<<B / 16, 256, 0, stream>>>(eo, gwb, sgwb, out, B);
}

// Round 5
// 725.472 us; speedup vs baseline: 1.0593x; 1.0593x over previous
//
#include <hip/hip_runtime.h>
#include <math.h>

typedef __attribute__((ext_vector_type(8))) _Float16 half8;  // 8 fp16 = 4 VGPRs
typedef __attribute__((ext_vector_type(8))) short short8;
typedef __attribute__((ext_vector_type(4))) float float4v;

// ---------------- fp16 helpers ---------------------------------------------
static __device__ __forceinline__ unsigned short f2h(float f) {
  union { _Float16 h; unsigned short u; } c;
  c.h = (_Float16)f;
  return c.u;
}
static __device__ __forceinline__ float h2f(unsigned short u) {
  union { unsigned short u; _Float16 h; } c;
  c.u = u;
  return (float)c.h;
}

// Direct global->LDS async copy, 16B per lane. LDS dest must be wave-uniform
// base; lane l lands at dest + l*16.
static __device__ __forceinline__ void gload16(const unsigned short* g,
                                               unsigned short* l) {
  __builtin_amdgcn_global_load_lds(
      (const __attribute__((address_space(1))) unsigned int*)g,
      (__attribute__((address_space(3))) unsigned int*)l, 16, 0, 0);
}

// ---------------------------------------------------------------------------
// split_pack: weights [nmat][K][N] fp32 -> packed swizzled fp16 hi/lo k-tiles.
// Output layout: [mat][kt = k/32][N rows][32 halves], chunk (row,q) stored at
// q' = q ^ ((row>>1)&3) -- the exact LDS image the GEMMs want.
// ---------------------------------------------------------------------------
__global__ __launch_bounds__(256)
void split_pack(const float* __restrict__ src, unsigned short* __restrict__ dh,
                unsigned short* __restrict__ dl, int K, int N) {
  __shared__ float t[32][33];
  src += (size_t)blockIdx.z * K * N;
  const size_t tsz = (size_t)N * 32;  // ushorts per tile
  const size_t tb = ((size_t)blockIdx.z * (K >> 5) + blockIdx.x) * tsz;
  const int k0 = blockIdx.x * 32, n0 = blockIdx.y * 32;
  const int tid = threadIdx.x;
  const int r = tid >> 3, c4 = (tid & 7) * 4;

  const float4 v = *(const float4*)(src + (size_t)(k0 + r) * N + n0 + c4);
  t[r][c4 + 0] = v.x; t[r][c4 + 1] = v.y; t[r][c4 + 2] = v.z; t[r][c4 + 3] = v.w;
  __syncthreads();

  const int sel = tid >> 7;          // 0 = hi, 1 = lo
  const int rl = (tid >> 2) & 31;    // row within this 32-row slab
  const int qq = tid & 3;            // logical 16B chunk within row
  short8 vv;
  #pragma unroll
  for (int j = 0; j < 8; ++j) {
    const float f = t[qq * 8 + j][rl];
    const unsigned short hb = f2h(f);
    ((unsigned short*)&vv)[j] = sel ? f2h(f - h2f(hb)) : hb;
  }
  unsigned short* dst = (sel ? dl : dh) + tb +
      (size_t)(n0 + rl) * 32 + (qq ^ ((rl >> 1) & 3)) * 8;
  *(short8*)dst = vv;
}

// ---------------------------------------------------------------------------
// LN (+bias) + ReLU epilogue over N cols (4 waves, col-split), then store
// fp16 bits to dst[row * dstride + col]. Ends with a barrier.
// ---------------------------------------------------------------------------
template<int N, int NT>
__device__ __forceinline__ void ln_store_f16(
    float4v (*acc)[4], int w, int m, int q,
    const float* __restrict__ bias, const float* __restrict__ gamma,
    const float* __restrict__ beta,
    unsigned short* __restrict__ dst, int dstride,
    float (*sumP)[4], float (*sqP)[4]) {
  constexpr int NW = N / 4;
  float cb[NT], cg[NT], cbt[NT];
  #pragma unroll
  for (int t = 0; t < NT; ++t) {
    const int col = w * NW + t * 16 + m;
    cb[t] = bias[col]; cg[t] = gamma[col]; cbt[t] = beta[col];
  }
  #pragma unroll
  for (int s = 0; s < 4; ++s)
    #pragma unroll
    for (int r = 0; r < 4; ++r) {
      float s1 = 0.f, s2 = 0.f;
      #pragma unroll
      for (int t = 0; t < NT; ++t) {
        const float v = acc[s][t][r] + cb[t];
        s1 += v; s2 += v * v;
      }
      #pragma unroll
      for (int off = 1; off < 16; off <<= 1) {
        s1 += __shfl_xor(s1, off, 16);
        s2 += __shfl_xor(s2, off, 16);
      }
      if (m == 0) {
        sumP[s * 16 + q * 4 + r][w] = s1;
        sqP[s * 16 + q * 4 + r][w] = s2;
      }
    }
  __syncthreads();
  #pragma unroll
  for (int s = 0; s < 4; ++s)
    #pragma unroll
    for (int r = 0; r < 4; ++r) {
      const int row = s * 16 + q * 4 + r;
      const float S1 = sumP[row][0] + sumP[row][1] + sumP[row][2] + sumP[row][3];
      const float S2 = sqP[row][0] + sqP[row][1] + sqP[row][2] + sqP[row][3];
      const float mean = S1 * (1.f / N);
      const float var = S2 * (1.f / N) - mean * mean;
      const float inv = rsqrtf(var + 1e-5f);
      #pragma unroll
      for (int t = 0; t < NT; ++t) {
        const float o =
            fmaxf((acc[s][t][r] + cb[t] - mean) * inv * cg[t] + cbt[t], 0.f);
        dst[row * dstride + w * NW + t * 16 + m] = f2h(o);
      }
    }
  __syncthreads();
}

// ---------------------------------------------------------------------------
// Fused expert tower (R2 numerics, bit-identical), pipelined.
// Phase 1: LDS double-buffered, counted drain vmcnt(2) (x prefetch rides the
//   barrier), setprio around MFMA cluster.
// Phases 2/3: reg-staged prefetch, lgkm-only drains (as R2) + setprio.
// Pool layout (ushort offsets), all overlays barrier-protected:
//   P1 loop : lA buf b = b*4096 (hi +0, lo +2048); lB buf b = 8192+b*16384
//             (hi +0, lo +8192).  Total 40960 = 81920 B.
//   sumP/sqP: 16384..17408 (dead sub-buffer region during all epilogues)
//   hbuf    : 24064..40960 (written in P1 epilogue after internal sync)
//   P2 B buf: 0..16384 (hi/lo)      P3 B buf: 0..8192 (hi/lo)
//   rp      : 0..8704 (P3 epilogue, after internal sync)
// ---------------------------------------------------------------------------
__global__ __launch_bounds__(256, 2)
void expert_tower(const float* __restrict__ x,
                  const unsigned short* __restrict__ w1h,
                  const unsigned short* __restrict__ w1l,
                  const float* __restrict__ eb1, const float* __restrict__ eg1,
                  const float* __restrict__ ebt1,
                  const unsigned short* __restrict__ w2h,
                  const unsigned short* __restrict__ w2l,
                  const float* __restrict__ eb2, const float* __restrict__ eg2,
                  const float* __restrict__ ebt2,
                  const unsigned short* __restrict__ w3h,
                  const unsigned short* __restrict__ w3l,
                  const float* __restrict__ eb3, const float* __restrict__ eg3,
                  const float* __restrict__ ebt3,
                  unsigned short* __restrict__ eo, int B) {
  __shared__ __align__(16) unsigned short pool[40960];
  float (*sumP)[4] = (float (*)[4])(pool + 16384);
  float (*sqP)[4]  = (float (*)[4])(pool + 16896);
  unsigned short* hbuf = pool + 24064;

  const int tid = threadIdx.x;
  const int w = tid >> 6, lane = tid & 63, m = lane & 15, q = lane >> 4;
  const int qs8 = (q ^ ((m >> 1) & 3)) * 8;  // swizzled 16B slot (x8 ushorts)
  const int wb = w * 512;                    // per-wave 1KB chunk, in ushorts
  const int m0 = blockIdx.x * 64;
  const int e = blockIdx.y;
  const int arow = tid >> 2, ap = tid & 3;
  const int aswz = arow * 32 + (ap ^ ((arow >> 1) & 3)) * 8;

  eb1 += (size_t)e * 256; eg1 += (size_t)e * 256; ebt1 += (size_t)e * 256;
  eb2 += (size_t)e * 256; eg2 += (size_t)e * 256; ebt2 += (size_t)e * 256;
  eb3 += (size_t)e * 128; eg3 += (size_t)e * 128; ebt3 += (size_t)e * 128;

  float4v acc[4][4];

  // ================= phase 1: K=512, N=256, 3-term, LDS dbuf ================
  #pragma unroll
  for (int s = 0; s < 4; ++s)
    #pragma unroll
    for (int t = 0; t < 4; ++t) acc[s][t] = (float4v){0.f, 0.f, 0.f, 0.f};

  const float* xrow = x + (size_t)(m0 + arow) * 512 + ap * 8;
  float4 f0 = *(const float4*)xrow;
  float4 f1 = *(const float4*)(xrow + 4);

  {  // prologue: stage tile 0 into buf0
    const float fv[8] = {f0.x, f0.y, f0.z, f0.w, f1.x, f1.y, f1.z, f1.w};
    half8 ra, rla;
    #pragma unroll
    for (int j = 0; j < 8; ++j) {
      const _Float16 hb = (_Float16)fv[j];
      ra[j] = hb;
      rla[j] = (_Float16)(fv[j] - (float)hb);
    }
    *(half8*)(pool + aswz) = ra;
    *(half8*)(pool + 2048 + aswz) = rla;
    const size_t tb = ((size_t)(e * 16)) * 8192 + tid * 8;
    #pragma unroll
    for (int i = 0; i < 4; ++i) {
      gload16(w1h + tb + i * 2048, pool + 8192 + wb + i * 2048);
      gload16(w1l + tb + i * 2048, pool + 8192 + 8192 + wb + i * 2048);
    }
    __builtin_amdgcn_sched_barrier(0);  // gloads issued before x loads (FIFO)
    f0 = *(const float4*)(xrow + 32);
    f1 = *(const float4*)(xrow + 36);
    __builtin_amdgcn_sched_barrier(0);
    asm volatile("s_waitcnt vmcnt(2) lgkmcnt(0)" ::: "memory");
    __builtin_amdgcn_sched_barrier(0);
    __builtin_amdgcn_s_barrier();
  }

  #pragma unroll 2
  for (int kt = 0; kt < 16; ++kt) {
    const int cur = kt & 1, nxt = cur ^ 1;
    if (kt < 15) {  // stage tile kt+1 into buf[nxt]
      const float fv[8] = {f0.x, f0.y, f0.z, f0.w, f1.x, f1.y, f1.z, f1.w};
      half8 ra, rla;
      #pragma unroll
      for (int j = 0; j < 8; ++j) {
        const _Float16 hb = (_Float16)fv[j];
        ra[j] = hb;
        rla[j] = (_Float16)(fv[j] - (float)hb);
      }
      *(half8*)(pool + nxt * 4096 + aswz) = ra;
      *(half8*)(pool + nxt * 4096 + 2048 + aswz) = rla;
      const size_t tb = ((size_t)(e * 16 + kt + 1)) * 8192 + tid * 8;
      #pragma unroll
      for (int i = 0; i < 4; ++i) {
        gload16(w1h + tb + i * 2048, pool + 8192 + nxt * 16384 + wb + i * 2048);
        gload16(w1l + tb + i * 2048,
                pool + 8192 + nxt * 16384 + 8192 + wb + i * 2048);
      }
      __builtin_amdgcn_sched_barrier(0);  // gloads before x loads (FIFO count)
      const int ktn = (kt < 14) ? kt + 2 : 15;
      f0 = *(const float4*)(xrow + ktn * 32);
      f1 = *(const float4*)(xrow + ktn * 32 + 4);
      __builtin_amdgcn_sched_barrier(0);  // pin staging before compute
    }
    __builtin_amdgcn_s_setprio(1);
    half8 ah[4], al[4];
    const unsigned short* ab = pool + cur * 4096;
    #pragma unroll
    for (int s = 0; s < 4; ++s) {
      const int off = (s * 16 + m) * 32 + qs8;
      ah[s] = *(const half8*)(ab + off);
      al[s] = *(const half8*)(ab + 2048 + off);
    }
    const unsigned short* bb = pool + 8192 + cur * 16384;
    #pragma unroll
    for (int t = 0; t < 4; ++t) {
      const int boff = (w * 64 + t * 16 + m) * 32 + qs8;
      const half8 bh = *(const half8*)(bb + boff);
      const half8 bl = *(const half8*)(bb + 8192 + boff);
      #pragma unroll
      for (int s = 0; s < 4; ++s) {
        acc[s][t] = __builtin_amdgcn_mfma_f32_16x16x32_f16(ah[s], bh, acc[s][t], 0, 0, 0);
        acc[s][t] = __builtin_amdgcn_mfma_f32_16x16x32_f16(al[s], bh, acc[s][t], 0, 0, 0);
        acc[s][t] = __builtin_amdgcn_mfma_f32_16x16x32_f16(ah[s], bl, acc[s][t], 0, 0, 0);
      }
    }
    __builtin_amdgcn_s_setprio(0);
    if (kt < 15) {
      __builtin_amdgcn_sched_barrier(0);  // keep MFMAs above the drain
      asm volatile("s_waitcnt vmcnt(2) lgkmcnt(0)" ::: "memory");
      __builtin_amdgcn_sched_barrier(0);
      __builtin_amdgcn_s_barrier();
    }
  }
  ln_store_f16<256, 4>(acc, w, m, q, eb1, eg1, ebt1, hbuf, 264, sumP, sqP);

  // ================= phase 2: K=256, N=256, 2-term, reg-staged ==============
  #pragma unroll
  for (int s = 0; s < 4; ++s)
    #pragma unroll
    for (int t = 0; t < 4; ++t) acc[s][t] = (float4v){0.f, 0.f, 0.f, 0.f};

  short8 rh[4], rl[4];
  {
    const size_t tb = ((size_t)(e * 8)) * 8192 + tid * 8;
    #pragma unroll
    for (int i = 0; i < 4; ++i) {
      rh[i] = *(const short8*)(w2h + tb + i * 2048);
      rl[i] = *(const short8*)(w2l + tb + i * 2048);
    }
  }
  for (int kt = 0; kt < 8; ++kt) {
    if (kt) __builtin_amdgcn_s_barrier();  // readers of tile kt-1 done
    #pragma unroll
    for (int i = 0; i < 4; ++i) {
      *(short8*)(pool + i * 2048 + tid * 8) = rh[i];
      *(short8*)(pool + 8192 + i * 2048 + tid * 8) = rl[i];
    }
    if (kt < 7) {  // prefetch tile kt+1 into regs (lands under MFMA below)
      const size_t tb = ((size_t)(e * 8 + kt + 1)) * 8192 + tid * 8;
      #pragma unroll
      for (int i = 0; i < 4; ++i) {
        rh[i] = *(const short8*)(w2h + tb + i * 2048);
        rl[i] = *(const short8*)(w2l + tb + i * 2048);
      }
    }
    __builtin_amdgcn_sched_barrier(0);
    asm volatile("s_waitcnt lgkmcnt(0)" ::: "memory");  // ds_writes visible
    __builtin_amdgcn_sched_barrier(0);
    __builtin_amdgcn_s_barrier();
    __builtin_amdgcn_s_setprio(1);
    half8 ah[4];
    #pragma unroll
    for (int s = 0; s < 4; ++s)
      ah[s] = *(const half8*)(hbuf + (s * 16 + m) * 264 + kt * 32 + q * 8);
    #pragma unroll
    for (int t = 0; t < 4; ++t) {
      const int boff = (w * 64 + t * 16 + m) * 32 + qs8;
      const half8 bh = *(const half8*)(pool + boff);
      const half8 bl = *(const half8*)(pool + 8192 + boff);
      #pragma unroll
      for (int s = 0; s < 4; ++s) {
        acc[s][t] = __builtin_amdgcn_mfma_f32_16x16x32_f16(ah[s], bh, acc[s][t], 0, 0, 0);
        acc[s][t] = __builtin_amdgcn_mfma_f32_16x16x32_f16(ah[s], bl, acc[s][t], 0, 0, 0);
      }
    }
    __builtin_amdgcn_s_setprio(0);
  }
  ln_store_f16<256, 4>(acc, w, m, q, eb2, eg2, ebt2, hbuf, 264, sumP, sqP);

  // ================= phase 3: K=256, N=128, 2-term, reg-staged ==============
  #pragma unroll
  for (int s = 0; s < 4; ++s)
    #pragma unroll
    for (int t = 0; t < 2; ++t) acc[s][t] = (float4v){0.f, 0.f, 0.f, 0.f};

  short8 sh[2], sl[2];
  {
    const size_t tb = ((size_t)(e * 8)) * 4096 + tid * 8;
    #pragma unroll
    for (int i = 0; i < 2; ++i) {
      sh[i] = *(const short8*)(w3h + tb + i * 2048);
      sl[i] = *(const short8*)(w3l + tb + i * 2048);
    }
  }
  for (int kt = 0; kt < 8; ++kt) {
    if (kt) __builtin_amdgcn_s_barrier();
    #pragma unroll
    for (int i = 0; i < 2; ++i) {
      *(short8*)(pool + i * 2048 + tid * 8) = sh[i];
      *(short8*)(pool + 4096 + i * 2048 + tid * 8) = sl[i];
    }
    if (kt < 7) {
      const size_t tb = ((size_t)(e * 8 + kt + 1)) * 4096 + tid * 8;
      #pragma unroll
      for (int i = 0; i < 2; ++i) {
        sh[i] = *(const short8*)(w3h + tb + i * 2048);
        sl[i] = *(const short8*)(w3l + tb + i * 2048);
      }
    }
    __builtin_amdgcn_sched_barrier(0);
    asm volatile("s_waitcnt lgkmcnt(0)" ::: "memory");
    __builtin_amdgcn_sched_barrier(0);
    __builtin_amdgcn_s_barrier();
    __builtin_amdgcn_s_setprio(1);
    half8 ah[4];
    #pragma unroll
    for (int s = 0; s < 4; ++s)
      ah[s] = *(const half8*)(hbuf + (s * 16 + m) * 264 + kt * 32 + q * 8);
    #pragma unroll
    for (int t = 0; t < 2; ++t) {
      const int boff = (w * 32 + t * 16 + m) * 32 + qs8;
      const half8 bh = *(const half8*)(pool + boff);
      const half8 bl = *(const half8*)(pool + 4096 + boff);
      #pragma unroll
      for (int s = 0; s < 4; ++s) {
        acc[s][t] = __builtin_amdgcn_mfma_f32_16x16x32_f16(ah[s], bh, acc[s][t], 0, 0, 0);
        acc[s][t] = __builtin_amdgcn_mfma_f32_16x16x32_f16(ah[s], bl, acc[s][t], 0, 0, 0);
      }
    }
    __builtin_amdgcn_s_setprio(0);
  }
  // epilogue 3 -> repack buffer (stride 136) -> coalesced fp16 stores to eo
  unsigned short* rp = pool;  // 64*136, overlays B buf (writes after sync)
  ln_store_f16<128, 2>(acc, w, m, q, eb3, eg3, ebt3, rp, 136, sumP, sqP);
  #pragma unroll
  for (int i = 0; i < 4; ++i) {
    const int c = tid + i * 256;
    const int rowc = c >> 4, c8 = c & 15;
    *(short8*)(eo + ((size_t)e * B + m0 + rowc) * 128 + c8 * 8) =
        *(const short8*)(rp + rowc * 136 + c8 * 8);
  }
}

// ---------------------------------------------------------------------------
// Gating GEMM + fused gate2: gh = relu(x@W^T + b1) entirely in-block, then
// softmax(gh @ w2 + b2) written straight to gwb/sgwb (bit-identical to the
// old gh round-trip: gh was exact fp32 both ways).
// sl = blockIdx.y (slice within this launch); slice_base offsets into tw.
// ---------------------------------------------------------------------------
template<int NOUT>
__global__ __launch_bounds__(256, 4)
void gate_gemm(const float* __restrict__ x, const unsigned short* __restrict__ twh,
               const unsigned short* __restrict__ twl,
               const float* __restrict__ b1, const float* __restrict__ w2,
               const float* __restrict__ b2, float* __restrict__ outw,
               int slice_base, int B) {
  __shared__ __align__(16) char smem[32768];
  unsigned short* gp = (unsigned short*)smem;  // GEMM phase
  float (*ghs)[65] = (float (*)[65])smem;      // epilogue overlay
  float* wls = (float*)(smem + 16640);
  float* bls = (float*)(smem + 16640 + 64 * NOUT * 4);

  const int tid = threadIdx.x;
  const int w = tid >> 6, lane = tid & 63, m = lane & 15, q = lane >> 4;
  const int qs8 = (q ^ ((m >> 1) & 3)) * 8;
  const int wb = w * 512;
  const int m0 = blockIdx.x * 64;
  const int sl = blockIdx.y;
  const int slice = slice_base + sl;
  const int arow = tid >> 2, ap = tid & 3;
  const int aswz = arow * 32 + (ap ^ ((arow >> 1) & 3)) * 8;
  const float* bias = b1 + (size_t)sl * 64;
  const float* w2p = w2 + (size_t)sl * 64 * NOUT;
  const float* b2p = b2 + (size_t)sl * NOUT;
  float* outp = outw + (size_t)sl * B * NOUT;

  float4v acc[4];
  #pragma unroll
  for (int s = 0; s < 4; ++s) acc[s] = (float4v){0.f, 0.f, 0.f, 0.f};

  const float* xrow = x + (size_t)(m0 + arow) * 512 + ap * 8;
  float4 f0 = *(const float4*)xrow;
  float4 f1 = *(const float4*)(xrow + 4);

  {  // prologue
    const float fv[8] = {f0.x, f0.y, f0.z, f0.w, f1.x, f1.y, f1.z, f1.w};
    half8 ra, rla;
    #pragma unroll
    for (int j = 0; j < 8; ++j) {
      const _Float16 hb = (_Float16)fv[j];
      ra[j] = hb;
      rla[j] = (_Float16)(fv[j] - (float)hb);
    }
    *(half8*)(gp + aswz) = ra;
    *(half8*)(gp + 2048 + aswz) = rla;
    const size_t tb = ((size_t)(slice * 16)) * 2048 + tid * 8;
    gload16(twh + tb, gp + 8192 + wb);
    gload16(twl + tb, gp + 8192 + 2048 + wb);
    __builtin_amdgcn_sched_barrier(0);
    f0 = *(const float4*)(xrow + 32);
    f1 = *(const float4*)(xrow + 36);
    __builtin_amdgcn_sched_barrier(0);
    asm volatile("s_waitcnt vmcnt(2) lgkmcnt(0)" ::: "memory");
    __builtin_amdgcn_sched_barrier(0);
    __builtin_amdgcn_s_barrier();
  }

  #pragma unroll 2
  for (int kt = 0; kt < 16; ++kt) {
    const int cur = kt & 1, nxt = cur ^ 1;
    if (kt < 15) {
      const float fv[8] = {f0.x, f0.y, f0.z, f0.w, f1.x, f1.y, f1.z, f1.w};
      half8 ra, rla;
      #pragma unroll
      for (int j = 0; j < 8; ++j) {
        const _Float16 hb = (_Float16)fv[j];
        ra[j] = hb;
        rla[j] = (_Float16)(fv[j] - (float)hb);
      }
      *(half8*)(gp + nxt * 4096 + aswz) = ra;
      *(half8*)(gp + nxt * 4096 + 2048 + aswz) = rla;
      const size_t tb = ((size_t)(slice * 16 + kt + 1)) * 2048 + tid * 8;
      gload16(twh + tb, gp + 8192 + nxt * 4096 + wb);
      gload16(twl + tb, gp + 8192 + nxt * 4096 + 2048 + wb);
      __builtin_amdgcn_sched_barrier(0);
      const int ktn = (kt < 14) ? kt + 2 : 15;
      f0 = *(const float4*)(xrow + ktn * 32);
      f1 = *(const float4*)(xrow + ktn * 32 + 4);
      __builtin_amdgcn_sched_barrier(0);
    }
    __builtin_amdgcn_s_setprio(1);
    const unsigned short* ab = gp + cur * 4096;
    const unsigned short* bb = gp + 8192 + cur * 4096;
    const int boff = (w * 16 + m) * 32 + qs8;
    const half8 bh = *(const half8*)(bb + boff);
    const half8 bl = *(const half8*)(bb + 2048 + boff);
    #pragma unroll
    for (int s = 0; s < 4; ++s) {
      const int aoff = (s * 16 + m) * 32 + qs8;
      const half8 ah = *(const half8*)(ab + aoff);
      const half8 al = *(const half8*)(ab + 2048 + aoff);
      acc[s] = __builtin_amdgcn_mfma_f32_16x16x32_f16(ah, bh, acc[s], 0, 0, 0);
      acc[s] = __builtin_amdgcn_mfma_f32_16x16x32_f16(al, bh, acc[s], 0, 0, 0);
      acc[s] = __builtin_amdgcn_mfma_f32_16x16x32_f16(ah, bl, acc[s], 0, 0, 0);
    }
    __builtin_amdgcn_s_setprio(0);
    if (kt < 15) {
      __builtin_amdgcn_sched_barrier(0);
      asm volatile("s_waitcnt vmcnt(2) lgkmcnt(0)" ::: "memory");
      __builtin_amdgcn_sched_barrier(0);
      __builtin_amdgcn_s_barrier();
    }
  }

  // ---- fused gate2 epilogue ----
  const float cb = bias[w * 16 + m];
  __syncthreads();  // all LDS reads of gp done before ghs overlay
  #pragma unroll
  for (int s = 0; s < 4; ++s)
    #pragma unroll
    for (int r = 0; r < 4; ++r)
      ghs[s * 16 + q * 4 + r][w * 16 + m] = fmaxf(acc[s][r] + cb, 0.f);
  for (int f = tid; f < 64 * NOUT; f += 256) wls[f] = w2p[f];
  if (tid < NOUT) bls[tid] = b2p[tid];
  __syncthreads();

  if (tid < 64) {
    float a[NOUT];
    #pragma unroll
    for (int n = 0; n < NOUT; ++n) a[n] = bls[n];
    for (int k = 0; k < 64; ++k) {
      const float g = ghs[tid][k];
      #pragma unroll
      for (int n = 0; n < NOUT; ++n) a[n] = fmaf(g, wls[k * NOUT + n], a[n]);
    }
    float mx = a[0];
    #pragma unroll
    for (int n = 1; n < NOUT; ++n) mx = fmaxf(mx, a[n]);
    float sum = 0.f;
    #pragma unroll
    for (int n = 0; n < NOUT; ++n) { a[n] = expf(a[n] - mx); sum += a[n]; }
    const float r = 1.f / sum;
    #pragma unroll
    for (int n = 0; n < NOUT; ++n)
      outp[(size_t)(m0 + tid) * NOUT + n] = a[n] * r;
  }
}

// ---------------------------------------------------------------------------
// Final combine: out[s][b][:] = sum_e coef(s,e,b) * eo[e][b][:]  (eo fp16)
// ---------------------------------------------------------------------------
__global__ __launch_bounds__(256)
void combine(const unsigned short* __restrict__ eo, const float* __restrict__ gw,
             const float* __restrict__ sgw, float* __restrict__ out, int B) {
  const int tid = threadIdx.x;
  const int gb = blockIdx.x * 16 + (tid >> 4);
  const int c0 = (tid & 15) * 8;

  float a[4][8];
  #pragma unroll
  for (int s = 0; s < 4; ++s)
    #pragma unroll
    for (int i = 0; i < 8; ++i) a[s][i] = 0.f;

  #pragma unroll
  for (int e = 0; e < 10; ++e) {
    const half8 vv = *(const half8*)(eo + ((size_t)e * B + gb) * 128 + c0);
    float f[8];
    #pragma unroll
    for (int i = 0; i < 8; ++i) f[i] = (float)vv[i];
    float c[4];
    c[3] = sgw[(size_t)gb * 10 + e];
    c[0] = c[1] = c[2] = 0.f;
    if (e < 4) {
      c[0] = gw[((size_t)0 * B + gb) * 6 + e];
      c[1] = gw[((size_t)1 * B + gb) * 6 + e];
      c[2] = gw[((size_t)2 * B + gb) * 6 + e];
    } else {
      const int tt = (e - 4) >> 1;
      c[tt] = gw[((size_t)tt * B + gb) * 6 + 4 + ((e - 4) & 1)];
    }
    #pragma unroll
    for (int s = 0; s < 4; ++s)
      #pragma unroll
      for (int i = 0; i < 8; ++i) a[s][i] = fmaf(c[s], f[i], a[s][i]);
  }

  #pragma unroll
  for (int s = 0; s < 4; ++s) {
    float* p = out + ((size_t)s * B + gb) * 128 + c0;
    const float4 v0 = {a[s][0], a[s][1], a[s][2], a[s][3]};
    const float4 v1 = {a[s][4], a[s][5], a[s][6], a[s][7]};
    *(float4*)p = v0;
    *(float4*)(p + 4) = v1;
  }
}

// ---------------------------------------------------------------------------
extern "C" void kernel_launch(void* const* d_in, const int* in_sizes, int n_in,
                              void* d_out, int out_size, void* d_ws, size_t ws_size,
                              hipStream_t stream) {
  const float* x     = (const float*)d_in[0];
  const float* ew1   = (const float*)d_in[1];
  const float* eb1   = (const float*)d_in[2];
  const float* eg1   = (const float*)d_in[3];
  const float* ebt1  = (const float*)d_in[4];
  const float* ew2   = (const float*)d_in[5];
  const float* eb2   = (const float*)d_in[6];
  const float* eg2   = (const float*)d_in[7];
  const float* ebt2  = (const float*)d_in[8];
  const float* ew3   = (const float*)d_in[9];
  const float* eb3   = (const float*)d_in[10];
  const float* eg3   = (const float*)d_in[11];
  const float* ebt3  = (const float*)d_in[12];
  const float* tg_w1 = (const float*)d_in[13];
  const float* tg_b1 = (const float*)d_in[14];
  const float* tg_w2 = (const float*)d_in[15];
  const float* tg_b2 = (const float*)d_in[16];
  const float* sg_w1 = (const float*)d_in[17];
  const float* sg_b1 = (const float*)d_in[18];
  const float* sg_w2 = (const float*)d_in[19];
  const float* sg_b2 = (const float*)d_in[20];
  float* out = (float*)d_out;

  const int B = 32768, D = 512, H = 256, O = 128, G = 64, E = 10;
  (void)D; (void)H; (void)O; (void)G;

  // ---- workspace (bytes), total ~97 MB ----
  char* p = (char*)d_ws;
  unsigned short* w1h  = (unsigned short*)p; p += (size_t)E * 16 * 8192 * 2;
  unsigned short* w1l  = (unsigned short*)p; p += (size_t)E * 16 * 8192 * 2;
  unsigned short* w2h  = (unsigned short*)p; p += (size_t)E * 8 * 8192 * 2;
  unsigned short* w2l  = (unsigned short*)p; p += (size_t)E * 8 * 8192 * 2;
  unsigned short* w3h  = (unsigned short*)p; p += (size_t)E * 8 * 4096 * 2;
  unsigned short* w3l  = (unsigned short*)p; p += (size_t)E * 8 * 4096 * 2;
  unsigned short* twh  = (unsigned short*)p; p += (size_t)4 * 16 * 2048 * 2;
  unsigned short* twl  = (unsigned short*)p; p += (size_t)4 * 16 * 2048 * 2;
  float* gwb  = (float*)p; p += (size_t)3 * B * 6 * 4;
  float* sgwb = (float*)p; p += (size_t)B * 10 * 4;
  unsigned short* eo = (unsigned short*)p;   // E*B*O fp16 = 83.9 MB

  // ---- 1. weight conversions (fp16 split, packed swizzled k-tiles) ----
  split_pack<<<dim3(16, 8, E), 256, 0, stream>>>(ew1, w1h, w1l, 512, 256);
  split_pack<<<dim3(8, 8, E), 256, 0, stream>>>(ew2, w2h, w2l, 256, 256);
  split_pack<<<dim3(8, 4, E), 256, 0, stream>>>(ew3, w3h, w3l, 256, 128);
  split_pack<<<dim3(16, 2, 3), 256, 0, stream>>>(tg_w1, twh, twl, 512, 64);
  split_pack<<<dim3(16, 2, 1), 256, 0, stream>>>(
      sg_w1, twh + (size_t)3 * 16 * 2048, twl + (size_t)3 * 16 * 2048, 512, 64);

  // ---- 2. gating (gate2 fused into the GEMM epilogue) ----
  gate_gemm<6><<<dim3(B / 64, 3), 256, 0, stream>>>(
      x, twh, twl, tg_b1, tg_w2, tg_b2, gwb, 0, B);
  gate_gemm<10><<<dim3(B / 64, 1), 256, 0, stream>>>(
      x, twh, twl, sg_b1, sg_w2, sg_b2, sgwb, 3, B);

  // ---- 3. fused expert towers: one launch, all experts ----
  expert_tower<<<dim3(B / 64, E), 256, 0, stream>>>(
      x, w1h, w1l, eb1, eg1, ebt1, w2h, w2l, eb2, eg2, ebt2,
      w3h, w3l, eb3, eg3, ebt3, eo, B);

  // ---- 4. combine ----
  combine<<<B / 16, 256, 0, stream>>>(eo, gwb, sgwb, out, B);
}